// Round 1
// baseline (363.339 us; speedup 1.0000x reference)
//
#include <hip/hip_runtime.h>

#define EMB 16

__global__ void zero_kernel(float* __restrict__ p, size_t n) {
    size_t i = (size_t)blockIdx.x * blockDim.x + threadIdx.x;
    size_t stride = (size_t)gridDim.x * blockDim.x;
    for (; i < n; i += stride) p[i] = 0.0f;
}

// Y[row,j] = X[row,:] @ W[:,j] + (b ? b[j] : 0).  One thread per (row, j).
__global__ void linear16_kernel(const float* __restrict__ X, const float* __restrict__ W,
                                const float* __restrict__ b, float* __restrict__ Y, int N) {
    int tid = blockIdx.x * blockDim.x + threadIdx.x;
    int row = tid >> 4;
    int j = tid & 15;
    if (row >= N) return;
    float acc = b ? b[j] : 0.0f;
    const float* xr = X + (size_t)row * EMB;
#pragma unroll
    for (int k = 0; k < EMB; ++k) acc = fmaf(xr[k], W[k * EMB + j], acc);
    Y[(size_t)row * EMB + j] = acc;
}

// One 16-lane group per edge; lane j handles component j.
// S[r,j] += relu(L[l,j] + ef[e]*We[j] + R[r,j]);  cnt[r] += 1 (lane 0).
__global__ void edge_kernel(const int* __restrict__ eidx, const float* __restrict__ ef,
                            const float* __restrict__ L, const float* __restrict__ R,
                            const float* __restrict__ We, float* __restrict__ S,
                            float* __restrict__ cnt, int E) {
    long long tid = (long long)blockIdx.x * blockDim.x + threadIdx.x;
    int e = (int)(tid >> 4);
    int j = (int)(tid & 15);
    if (e >= E) return;
    int l = eidx[e];
    int r = eidx[E + e];
    float v = L[(size_t)l * EMB + j] + ef[e] * We[j] + R[(size_t)r * EMB + j];
    v = fmaxf(v, 0.0f);
    atomicAdd(&S[(size_t)r * EMB + j], v);
    if (j == 0) atomicAdd(&cnt[r], 1.0f);
}

// Per right node: agg = S@Wf + cnt*bf ; post = relu(agg)@Wp + bp ;
// h=[post, rf] ; out = relu(h@Wo1 + bo1)@Wo2 + bo2.  One thread per node.
__global__ void final_kernel(const float* __restrict__ S, const float* __restrict__ cnt,
                             const float* __restrict__ rf,
                             const float* __restrict__ Wf, const float* __restrict__ bf,
                             const float* __restrict__ Wp, const float* __restrict__ bp,
                             const float* __restrict__ Wo1, const float* __restrict__ bo1,
                             const float* __restrict__ Wo2, const float* __restrict__ bo2,
                             float* __restrict__ out, int N) {
    __shared__ float sWf[256], sWp[256], sWo1[512], sWo2[256];
    __shared__ float sb[64];  // [bf | bp | bo1 | bo2]
    int t = threadIdx.x;
    for (int i = t; i < 256; i += 256) { sWf[i] = Wf[i]; sWp[i] = Wp[i]; sWo2[i] = Wo2[i]; }
    for (int i = t; i < 512; i += 256) sWo1[i] = Wo1[i];
    if (t < 16) { sb[t] = bf[t]; sb[16 + t] = bp[t]; sb[32 + t] = bo1[t]; sb[48 + t] = bo2[t]; }
    __syncthreads();

    int r = blockIdx.x * blockDim.x + t;
    if (r >= N) return;

    float s[16], x[16], y[16], rv[16], z[16], o[16];
    const float4* Sp = (const float4*)(S + (size_t)r * EMB);
    const float4* Rp = (const float4*)(rf + (size_t)r * EMB);
#pragma unroll
    for (int k = 0; k < 4; ++k) {
        float4 v = Sp[k];
        s[4 * k] = v.x; s[4 * k + 1] = v.y; s[4 * k + 2] = v.z; s[4 * k + 3] = v.w;
        float4 w = Rp[k];
        rv[4 * k] = w.x; rv[4 * k + 1] = w.y; rv[4 * k + 2] = w.z; rv[4 * k + 3] = w.w;
    }
    float c = cnt[r];

#pragma unroll
    for (int j = 0; j < 16; ++j) {
        float a = c * sb[j];
#pragma unroll
        for (int k = 0; k < 16; ++k) a = fmaf(s[k], sWf[k * 16 + j], a);
        x[j] = fmaxf(a, 0.0f);
    }
#pragma unroll
    for (int j = 0; j < 16; ++j) {
        float a = sb[16 + j];
#pragma unroll
        for (int k = 0; k < 16; ++k) a = fmaf(x[k], sWp[k * 16 + j], a);
        y[j] = a;
    }
#pragma unroll
    for (int j = 0; j < 16; ++j) {
        float a = sb[32 + j];
#pragma unroll
        for (int k = 0; k < 16; ++k) a = fmaf(y[k], sWo1[k * 16 + j], a);
#pragma unroll
        for (int k = 0; k < 16; ++k) a = fmaf(rv[k], sWo1[(16 + k) * 16 + j], a);
        z[j] = fmaxf(a, 0.0f);
    }
#pragma unroll
    for (int j = 0; j < 16; ++j) {
        float a = sb[48 + j];
#pragma unroll
        for (int k = 0; k < 16; ++k) a = fmaf(z[k], sWo2[k * 16 + j], a);
        o[j] = a;
    }
    float4* Op = (float4*)(out + (size_t)r * EMB);
#pragma unroll
    for (int k = 0; k < 4; ++k)
        Op[k] = make_float4(o[4 * k], o[4 * k + 1], o[4 * k + 2], o[4 * k + 3]);
}

extern "C" void kernel_launch(void* const* d_in, const int* in_sizes, int n_in,
                              void* d_out, int out_size, void* d_ws, size_t ws_size,
                              hipStream_t stream) {
    const float* lf     = (const float*)d_in[0];
    const int*   eidx   = (const int*)d_in[1];
    const float* ef     = (const float*)d_in[2];
    const float* rf     = (const float*)d_in[3];
    const float* W_left = (const float*)d_in[4];
    const float* b_left = (const float*)d_in[5];
    const float* W_edge = (const float*)d_in[6];
    const float* W_right= (const float*)d_in[7];
    const float* W_final= (const float*)d_in[8];
    const float* b_final= (const float*)d_in[9];
    const float* W_post = (const float*)d_in[10];
    const float* b_post = (const float*)d_in[11];
    const float* W_out1 = (const float*)d_in[12];
    const float* b_out1 = (const float*)d_in[13];
    const float* W_out2 = (const float*)d_in[14];
    const float* b_out2 = (const float*)d_in[15];

    int n_left  = in_sizes[0] / EMB;
    int E       = in_sizes[2];
    int n_right = in_sizes[3] / EMB;
    float* out = (float*)d_out;

    float* L   = (float*)d_ws;
    float* R   = L + (size_t)n_left * EMB;
    float* S   = R + (size_t)n_right * EMB;
    float* cnt = S + (size_t)n_right * EMB;  // cnt directly follows S

    // zero S and cnt (contiguous)
    zero_kernel<<<2048, 256, 0, stream>>>(S, (size_t)n_right * (EMB + 1));

    linear16_kernel<<<(n_left * EMB + 255) / 256, 256, 0, stream>>>(lf, W_left, b_left, L, n_left);
    linear16_kernel<<<(n_right * EMB + 255) / 256, 256, 0, stream>>>(rf, W_right, nullptr, R, n_right);

    long long ethreads = (long long)E * EMB;
    edge_kernel<<<(unsigned)((ethreads + 255) / 256), 256, 0, stream>>>(eidx, ef, L, R, W_edge, S, cnt, E);

    final_kernel<<<(n_right + 255) / 256, 256, 0, stream>>>(S, cnt, rf,
        W_final, b_final, W_post, b_post, W_out1, b_out1, W_out2, b_out2, out, n_right);
}